// Round 2
// baseline (198.912 us; speedup 1.0000x reference)
//
#include <hip/hip_runtime.h>
#include <stdint.h>

// R2Ntab: out[b] = sum_r [rule r fires on row b] + b_or, where rule r fires iff
//   every unmasked positive-weight feature is 1 AND no unmasked negative-weight
//   feature is 1 (deficit == 0  <=>  h = b_and - deficit > 0.999999, b_and == 1).
// Pure 256-bit boolean logic per (row, rule) -> memory-bound on reading x (134 MB).
// R2: prefetch depth 4 (4 KB in flight per wave) to push toward the HBM BW floor.

#define B_ROWS 131072
#define F_FEAT 256
#define R_RULES 128

// Build per-rule bitmasks in ballot bit order:
//   ballot word j (j=0..3), bit l  <->  feature f = l*4 + j
// Stored as uint32 masks[rule][16] = { pos[8], neg[8] }.
// w_or <= 0 => rule can never count: set pos=neg=~0 (test always fails).
__global__ __launch_bounds__(256) void build_masks_kernel(
    const float* __restrict__ w_and, const float* __restrict__ w_cancel,
    const float* __restrict__ w_or, uint32_t* __restrict__ masks)
{
    const int r = blockIdx.x;        // one rule per block
    const int t = threadIdx.x;
    const int j = t >> 6;            // ballot word index 0..3 (one wave per word)
    const int l = t & 63;            // lane
    const int f = l * 4 + j;         // feature covered by bit l of word j

    const float wc = w_cancel[f];
    const float w  = w_and[r * F_FEAT + f];
    const bool masked = (wc < 0.0f); // col_mask == (w_cancel < 0) since x is 0/1
    unsigned long long pb = __ballot((!masked) && (w > 0.0f));
    unsigned long long nb = __ballot((!masked) && (w < 0.0f));
    if (w_or[r] <= 0.0f) { pb = ~0ull; nb = ~0ull; }
    if (l == 0) {
        masks[r * 16 + j * 2 + 0]     = (uint32_t)pb;
        masks[r * 16 + j * 2 + 1]     = (uint32_t)(pb >> 32);
        masks[r * 16 + 8 + j * 2 + 0] = (uint32_t)nb;
        masks[r * 16 + 8 + j * 2 + 1] = (uint32_t)(nb >> 32);
    }
}

// Each wave handles 16 consecutive rows; block (4 waves) handles 64 rows.
// Per row: one coalesced float4 load per lane (whole 1 KB row per wave-instruction),
// 4 ballots pack the row into 8 wave-uniform u32 words, each lane tests 2 rules.
// Software pipeline depth 4: 4 row-loads outstanding per wave at all times.
__global__ __launch_bounds__(256) void r2ntab_main_kernel(
    const float4* __restrict__ x4, const uint32_t* __restrict__ masks,
    const float* __restrict__ b_or, float* __restrict__ out)
{
    const int lane    = threadIdx.x & 63;
    const int wave    = threadIdx.x >> 6;
    const int rowBase = blockIdx.x * 64 + wave * 16;

    // Per-lane rule pair: rules 2*lane and 2*lane+1 (8 KB total, L1/L2-hot).
    uint32_t p0[8], n0[8], p1[8], n1[8];
    const uint32_t* __restrict__ m0 = masks + (size_t)(2 * lane) * 16;
    const uint32_t* __restrict__ m1 = masks + (size_t)(2 * lane + 1) * 16;
    #pragma unroll
    for (int w = 0; w < 8; ++w) {
        p0[w] = m0[w];     n0[w] = m0[8 + w];
        p1[w] = m1[w];     n1[w] = m1[8 + w];
    }

    const float borv = b_or[0];
    float res = 0.0f;

    const float4* __restrict__ base = x4 + (size_t)rowBase * 64 + lane;

    // Prime the pipeline: rows 0..3 in flight.
    float4 buf[4];
    #pragma unroll
    for (int k = 0; k < 4; ++k) buf[k] = base[(size_t)k * 64];

    #pragma unroll
    for (int i = 0; i < 16; ++i) {
        const float4 cur = buf[i & 3];
        if (i + 4 < 16) buf[i & 3] = base[(size_t)(i + 4) * 64];  // keep 4 loads in flight

        // Pack row bits: word j bit l = feature l*4+j (x is exactly 0.0 or 1.0).
        const unsigned long long bb0 = __ballot(cur.x > 0.5f);
        const unsigned long long bb1 = __ballot(cur.y > 0.5f);
        const unsigned long long bb2 = __ballot(cur.z > 0.5f);
        const unsigned long long bb3 = __ballot(cur.w > 0.5f);
        const uint32_t xw[8] = {
            (uint32_t)bb0, (uint32_t)(bb0 >> 32),
            (uint32_t)bb1, (uint32_t)(bb1 >> 32),
            (uint32_t)bb2, (uint32_t)(bb2 >> 32),
            (uint32_t)bb3, (uint32_t)(bb3 >> 32)
        };

        // Rule hit <=> OR_w [ (~x & pos) | (x & neg) ] == 0   (2x v_and_or_b32 per word)
        uint32_t acc0 = 0, acc1 = 0;
        #pragma unroll
        for (int w = 0; w < 8; ++w) {
            const uint32_t xv = xw[w], txv = ~xv;
            acc0 |= (txv & p0[w]) | (xv & n0[w]);
            acc1 |= (txv & p1[w]) | (xv & n1[w]);
        }

        // Count firing rules across the wave (result is wave-uniform).
        const int cnt = __popcll(__ballot(acc0 == 0)) + __popcll(__ballot(acc1 == 0));
        const float val = (float)cnt + borv;   // w_or>0 folded into masks; b_and==1 folded in
        if (lane == i) res = val;              // lane i keeps row i's result
    }
    if (lane < 16) out[rowBase + lane] = res;  // coalesced 64 B store per wave
}

extern "C" void kernel_launch(void* const* d_in, const int* in_sizes, int n_in,
                              void* d_out, int out_size, void* d_ws, size_t ws_size,
                              hipStream_t stream) {
    const float* x        = (const float*)d_in[0];  // [B, F] binary 0/1
    const float* w_cancel = (const float*)d_in[1];  // [F]
    const float* w_and    = (const float*)d_in[2];  // [R, F]
    // d_in[3] = b_and [R], frozen at 1.0 (folded into the deficit==0 test)
    const float* w_or     = (const float*)d_in[4];  // [O, R] = [1, 128]
    const float* b_or     = (const float*)d_in[5];  // [O] = [-0.5]

    uint32_t* masks = (uint32_t*)d_ws;              // 128 rules * 16 u32 = 8 KB
    float* out = (float*)d_out;                     // [B] floats

    build_masks_kernel<<<R_RULES, 256, 0, stream>>>(w_and, w_cancel, w_or, masks);
    r2ntab_main_kernel<<<B_ROWS / 64, 256, 0, stream>>>(
        (const float4*)x, masks, b_or, out);
}

// Round 4
// 191.928 us; speedup vs baseline: 1.0364x; 1.0364x over previous
//
#include <hip/hip_runtime.h>
#include <stdint.h>

// R2Ntab: out[b] = sum_r [rule r fires on row b] + b_or, where rule r fires iff
//   every unmasked positive-weight feature is 1 AND no unmasked negative-weight
//   feature is 1 (deficit == 0  <=>  h = b_and - deficit > 0.999999, b_and == 1).
// Pure 256-bit boolean logic per (row, rule) -> memory-bound on reading x (134 MB).
// R4: R3 with ext_vector_type float4 so __builtin_nontemporal_load compiles.

#define B_ROWS 131072
#define F_FEAT 256
#define R_RULES 128
#define ROWS_PER_WAVE 8

typedef float fvec4 __attribute__((ext_vector_type(4)));

// Build per-rule bitmasks in ballot bit order:
//   ballot word j (j=0..3), bit l  <->  feature f = l*4 + j
// Stored as uint32 masks[rule][16] = { pos[8], neg[8] }.
// w_or <= 0 => rule can never count: set pos=neg=~0 (test always fails).
__global__ __launch_bounds__(256) void build_masks_kernel(
    const float* __restrict__ w_and, const float* __restrict__ w_cancel,
    const float* __restrict__ w_or, uint32_t* __restrict__ masks)
{
    const int r = blockIdx.x;        // one rule per block
    const int t = threadIdx.x;
    const int j = t >> 6;            // ballot word index 0..3 (one wave per word)
    const int l = t & 63;            // lane
    const int f = l * 4 + j;         // feature covered by bit l of word j

    const float wc = w_cancel[f];
    const float w  = w_and[r * F_FEAT + f];
    const bool masked = (wc < 0.0f); // col_mask == (w_cancel < 0) since x is 0/1
    unsigned long long pb = __ballot((!masked) && (w > 0.0f));
    unsigned long long nb = __ballot((!masked) && (w < 0.0f));
    if (w_or[r] <= 0.0f) { pb = ~0ull; nb = ~0ull; }
    if (l == 0) {
        masks[r * 16 + j * 2 + 0]     = (uint32_t)pb;
        masks[r * 16 + j * 2 + 1]     = (uint32_t)(pb >> 32);
        masks[r * 16 + 8 + j * 2 + 0] = (uint32_t)nb;
        masks[r * 16 + 8 + j * 2 + 1] = (uint32_t)(nb >> 32);
    }
}

// Each wave handles 8 consecutive rows; block (4 waves) handles 32 rows.
// Per row: one coalesced float4 load per lane (whole 1 KB row per wave-instruction),
// 4 ballots pack the row into 8 wave-uniform u32 words, each lane tests 2 rules.
__global__ __launch_bounds__(256) void r2ntab_main_kernel(
    const fvec4* __restrict__ x4, const uint32_t* __restrict__ masks,
    const float* __restrict__ b_or, float* __restrict__ out)
{
    const int lane    = threadIdx.x & 63;
    const int wave    = threadIdx.x >> 6;
    const int rowBase = blockIdx.x * (4 * ROWS_PER_WAVE) + wave * ROWS_PER_WAVE;

    // Per-lane rule pair: rules 2*lane and 2*lane+1 (8 KB total, L1/L2-hot).
    uint32_t p0[8], n0[8], p1[8], n1[8];
    const uint32_t* __restrict__ m0 = masks + (size_t)(2 * lane) * 16;
    const uint32_t* __restrict__ m1 = masks + (size_t)(2 * lane + 1) * 16;
    #pragma unroll
    for (int w = 0; w < 8; ++w) {
        p0[w] = m0[w];     n0[w] = m0[8 + w];
        p1[w] = m1[w];     n1[w] = m1[8 + w];
    }

    const float borv = b_or[0];
    float res = 0.0f;

    const fvec4* __restrict__ base = x4 + (size_t)rowBase * 64 + lane;

    // Issue all 8 row-loads up front (nontemporal: pure streaming, skip cache).
    fvec4 buf[ROWS_PER_WAVE];
    #pragma unroll
    for (int k = 0; k < ROWS_PER_WAVE; ++k)
        buf[k] = __builtin_nontemporal_load(base + (size_t)k * 64);

    #pragma unroll
    for (int i = 0; i < ROWS_PER_WAVE; ++i) {
        const fvec4 cur = buf[i];

        // Pack row bits: word j bit l = feature l*4+j (x is exactly 0.0 or 1.0).
        const unsigned long long bb0 = __ballot(cur.x > 0.5f);
        const unsigned long long bb1 = __ballot(cur.y > 0.5f);
        const unsigned long long bb2 = __ballot(cur.z > 0.5f);
        const unsigned long long bb3 = __ballot(cur.w > 0.5f);
        const uint32_t xw[8] = {
            (uint32_t)bb0, (uint32_t)(bb0 >> 32),
            (uint32_t)bb1, (uint32_t)(bb1 >> 32),
            (uint32_t)bb2, (uint32_t)(bb2 >> 32),
            (uint32_t)bb3, (uint32_t)(bb3 >> 32)
        };

        // Rule hit <=> OR_w [ (~x & pos) | (x & neg) ] == 0   (2x v_and_or_b32 per word)
        uint32_t acc0 = 0, acc1 = 0;
        #pragma unroll
        for (int w = 0; w < 8; ++w) {
            const uint32_t xv = xw[w], txv = ~xv;
            acc0 |= (txv & p0[w]) | (xv & n0[w]);
            acc1 |= (txv & p1[w]) | (xv & n1[w]);
        }

        // Count firing rules across the wave (result is wave-uniform).
        const int cnt = __popcll(__ballot(acc0 == 0)) + __popcll(__ballot(acc1 == 0));
        const float val = (float)cnt + borv;   // w_or>0 folded into masks; b_and==1 folded in
        if (lane == i) res = val;              // lane i keeps row i's result
    }
    if (lane < ROWS_PER_WAVE) out[rowBase + lane] = res;  // 32 B store per wave
}

extern "C" void kernel_launch(void* const* d_in, const int* in_sizes, int n_in,
                              void* d_out, int out_size, void* d_ws, size_t ws_size,
                              hipStream_t stream) {
    const float* x        = (const float*)d_in[0];  // [B, F] binary 0/1
    const float* w_cancel = (const float*)d_in[1];  // [F]
    const float* w_and    = (const float*)d_in[2];  // [R, F]
    // d_in[3] = b_and [R], frozen at 1.0 (folded into the deficit==0 test)
    const float* w_or     = (const float*)d_in[4];  // [O, R] = [1, 128]
    const float* b_or     = (const float*)d_in[5];  // [O] = [-0.5]

    uint32_t* masks = (uint32_t*)d_ws;              // 128 rules * 16 u32 = 8 KB
    float* out = (float*)d_out;                     // [B] floats

    build_masks_kernel<<<R_RULES, 256, 0, stream>>>(w_and, w_cancel, w_or, masks);
    r2ntab_main_kernel<<<B_ROWS / (4 * ROWS_PER_WAVE), 256, 0, stream>>>(
        (const fvec4*)x, masks, b_or, out);
}